// Round 5
// baseline (313.306 us; speedup 1.0000x reference)
//
#include <hip/hip_runtime.h>

typedef unsigned short u16;
typedef unsigned int   u32;
typedef __bf16 bf16x8 __attribute__((ext_vector_type(8)));
typedef float  f32x4  __attribute__((ext_vector_type(4)));

__device__ __forceinline__ u16 f2b(float f) {
  u32 u = __builtin_bit_cast(u32, f);
  u = (u + 0x7fffu + ((u >> 16) & 1u)) >> 16;   // RNE
  return (u16)u;
}
__device__ __forceinline__ float b2f(u16 h) {
  u32 u = ((u32)h) << 16;
  return __builtin_bit_cast(float, u);
}
__device__ __forceinline__ float ld_in(const void* p, size_t idx, int isf32) {
  return isf32 ? ((const float*)p)[idx] : b2f(((const u16*)p)[idx]);
}
// async 16B global->LDS; HW semantics: LDS dest = wave-uniform base + lane*16
__device__ __forceinline__ void async_cp16(const u16* g, u16* l) {
  __builtin_amdgcn_global_load_lds(
      (const __attribute__((address_space(1))) void*)g,
      (__attribute__((address_space(3))) void*)l, 16, 0, 0);
}

// Constants: BS=1024, CH=3, IMG=64, K=16, NC=10, HID=1024, LAT=128
// OH=4, L=16, PD=768, M=16384.
#define RECON_ELEMS 12582912   // 1024*3*64*64
// xb: per batch 12544 bf16 = [image 12288 | c 10 | zeros 246]
#define XB_STRIDE 12544

// ---------------------------------------------------------------------------
// dtype detector: bf16 uniform[0,1) values are u16 in [0,0x3F80], sign=0.
// ---------------------------------------------------------------------------
__global__ __launch_bounds__(256) void detect_f32(const u16* __restrict__ x,
                                                  int* __restrict__ flag) {
  __shared__ int s;
  if (threadIdx.x == 0) s = 0;
  __syncthreads();
  int bad = 0;
  for (int i = threadIdx.x; i < 2048; i += 256) {
    u16 u = x[i];
    if ((u & 0x8000u) || (u > 0x3F80u)) bad = 1;
  }
  if (bad) atomicOr(&s, 1);
  __syncthreads();
  if (threadIdx.x == 0) *flag = s;
}

// ---------------------------------------------------------------------------
// cvt_x: x (f32 or bf16) -> xb bf16 [12288 image | c(10) | zeros(246)] / batch.
// enc1 stages A-tiles straight from xb (per-lane gload_lds source addresses
// carry the patch permutation). 75MB traffic, memory-bound.
// ---------------------------------------------------------------------------
__global__ __launch_bounds__(256) void cvt_x(const void* __restrict__ x,
                                             const void* __restrict__ c,
                                             u16* __restrict__ xb,
                                             const int* __restrict__ flag) {
  const int g = blockIdx.x * 256 + threadIdx.x;
  const int isf = *flag;
  if (g < 1572864) {                       // 12582912/8 image groups of 8
    const size_t i = (size_t)g * 8;
    const int b = (int)(i / 12288);
    const int r = (int)(i - (size_t)b * 12288);
    u16* dst = xb + (size_t)b * XB_STRIDE + r;
    if (isf) {
      const float* s = (const float*)x + i;
      float4 f0 = *(const float4*)(s);
      float4 f1 = *(const float4*)(s + 4);
      dst[0] = f2b(f0.x); dst[1] = f2b(f0.y); dst[2] = f2b(f0.z); dst[3] = f2b(f0.w);
      dst[4] = f2b(f1.x); dst[5] = f2b(f1.y); dst[6] = f2b(f1.z); dst[7] = f2b(f1.w);
    } else {
      *(int4*)dst = *(const int4*)((const u16*)x + i);
    }
  } else if (g < 1605632) {                // tail: 1024 batches x 32 groups
    const int t8 = g - 1572864;
    const int b = t8 >> 5;
    const int k8 = (t8 & 31) * 8;
    u16* dst = xb + (size_t)b * XB_STRIDE + 12288 + k8;
#pragma unroll
    for (int j = 0; j < 8; ++j) {
      const int col = k8 + j;
      dst[j] = (col < 10) ? f2b(ld_in(c, (size_t)b * 10 + col, isf)) : (u16)0;
    }
  }
}

// ---------------------------------------------------------------------------
// Fused weight prep: 4 transposes in one dispatch (blockIdx.z selects).
// dst (N x Kpad) = src(Ksrc x N)^T, zero-pad k>=Ksrc. 32x32 LDS tile.
// ---------------------------------------------------------------------------
__global__ __launch_bounds__(256) void prep_weights(const void* __restrict__ ew1,
                                                    const void* __restrict__ ew2,
                                                    const void* __restrict__ dw1,
                                                    const void* __restrict__ dw2,
                                                    u16* __restrict__ W1t,
                                                    u16* __restrict__ EW2t,
                                                    u16* __restrict__ W3t,
                                                    u16* __restrict__ DW2t,
                                                    const int* __restrict__ flag) {
  const int z = blockIdx.z;
  const void* src; u16* dst; int N, Kpad, Ksrc;
  if (z == 0)      { src = ew1; dst = W1t;  N = 1024; Kpad = 800;  Ksrc = 778;  }
  else if (z == 1) { src = ew2; dst = EW2t; N = 256;  Kpad = 1024; Ksrc = 1024; }
  else if (z == 2) { src = dw1; dst = W3t;  N = 1024; Kpad = 160;  Ksrc = 138;  }
  else             { src = dw2; dst = DW2t; N = 768;  Kpad = 1024; Ksrc = 1024; }
  const int k0 = blockIdx.x * 32, n0 = blockIdx.y * 32;
  if (k0 >= Kpad || n0 >= N) return;
  __shared__ float t[32][33];
  const int tx = threadIdx.x & 31, ty = threadIdx.x >> 5;   // 32 x 8
  const int isf = *flag;
#pragma unroll
  for (int j = 0; j < 4; ++j) {
    int k = k0 + ty + j * 8;
    t[ty + j * 8][tx] = (k < Ksrc) ? ld_in(src, (size_t)k * N + n0 + tx, isf) : 0.0f;
  }
  __syncthreads();
#pragma unroll
  for (int j = 0; j < 4; ++j) {
    int n = n0 + ty + j * 8;
    dst[(size_t)n * Kpad + k0 + tx] = f2b(t[tx][ty + j * 8]);
  }
}

// ---------------------------------------------------------------------------
// enc1_k: h = relu(patch(x)|c @ W1t^T + b1). 64-row slab per block, grid =
// R/64 = 256 -> 1 block/CU. Waves own 128 private N-cols; B-fragments load
// DIRECTLY from W1t (L2-resident, lane reads Bt[col][k0+quad*8] = 16B; a
// wave's 16 rows x 64B contiguous segments). Only the 4KB A-tile transits
// LDS (dbuf, xb patch-gather source, proven r3/r4 swizzle pair). Ledger:
// plain B loads mix with manual gload_lds -> ONLY vmcnt(0) drains used.
// Per step: [w<4: stage A(t+1)] ; 4 ds_read A-frags ; 8 B-loads ; lgkm(0);
// 32 MFMA ; vmcnt(0)+barrier.
// ---------------------------------------------------------------------------
__global__ __launch_bounds__(512, 2) void enc1_k(const u16* __restrict__ xb,
                                                 const u16* __restrict__ W1t,
                                                 const void* __restrict__ eb1,
                                                 u16* __restrict__ hc,
                                                 int rowOff,
                                                 const int* __restrict__ flag) {
  __shared__ __align__(16) u16 As[2][2048];    // 2 x 4 KB
  const int bid = blockIdx.x;
  const int lrowBase = bid * 64;               // chunk-local
  const int tid = threadIdx.x;
  const int lane = tid & 63, w = tid >> 6;
  const int l16 = lane & 15, quad = lane >> 4;
  const int swq = quad ^ ((l16 >> 1) & 3);

  const int isf = *flag;
  float bv[8];
#pragma unroll
  for (int cb = 0; cb < 8; ++cb)
    bv[cb] = ld_in(eb1, w * 128 + cb * 16 + l16, isf);

  // A staging map (waves 0..3): slot s = w*64+lane in [0,256): r=s>>2,
  // chunk q=(s&3)^((r>>1)&3); src = xb patch gather (proven round-4 formula)
  const int s = (w & 3) * 64 + lane;
  const int r = s >> 2, q = (s & 3) ^ ((r >> 1) & 3);
  const int grow = rowOff + lrowBase + r;
  const int bb = grow >> 4, ll = grow & 15;
  const int base1 = bb * XB_STRIDE + (ll >> 2) * 1024 + (ll & 3) * 16;
  const int base2 = bb * XB_STRIDE + 11520;    // +k -> b*12544+12288+(k-768)
  const int kq = q * 8;

  // B bases: col = w*128 + cb*16 + l16, k-chunk = quad
  const u16* bB[8];
#pragma unroll
  for (int cb = 0; cb < 8; ++cb)
    bB[cb] = W1t + (size_t)(w * 128 + cb * 16 + l16) * 800 + quad * 8;

  f32x4 acc[4][8] = {};

#define A_ADDR(tt) (xb + (((kq + (tt) * 32) < 768)                              \
      ? base1 + (((kq + (tt) * 32) >> 8) << 12) +                               \
        ((((kq + (tt) * 32) >> 4) & 15) << 6) + ((kq + (tt) * 32) & 15)         \
      : base2 + kq + (tt) * 32))

  if (w < 4) async_cp16(A_ADDR(0), &As[0][s * 8]);
  asm volatile("s_waitcnt vmcnt(0)" ::: "memory");
  __builtin_amdgcn_s_barrier();

  for (int t = 0; t < 25; ++t) {
    const int p = t & 1;
    if (w < 4 && t + 1 < 25) async_cp16(A_ADDR(t + 1), &As[p ^ 1][s * 8]);
    bf16x8 a[4], b[8];
#pragma unroll
    for (int mr = 0; mr < 4; ++mr)
      a[mr] = *(const bf16x8*)(&As[p][(mr * 16 + l16) * 32 + swq * 8]);
#pragma unroll
    for (int cb = 0; cb < 8; ++cb)
      b[cb] = *(const bf16x8*)(bB[cb] + t * 32);
    asm volatile("s_waitcnt lgkmcnt(0)" ::: "memory");
    __builtin_amdgcn_sched_barrier(0);
    __builtin_amdgcn_s_setprio(1);
#pragma unroll
    for (int mr = 0; mr < 4; ++mr)
#pragma unroll
      for (int cb = 0; cb < 8; ++cb)
        acc[mr][cb] = __builtin_amdgcn_mfma_f32_16x16x32_bf16(a[mr], b[cb], acc[mr][cb], 0, 0, 0);
    __builtin_amdgcn_s_setprio(0);
    __builtin_amdgcn_sched_barrier(0);
    asm volatile("s_waitcnt vmcnt(0)" ::: "memory");   // A(t+1) landed; B(t) done
    __builtin_amdgcn_s_barrier();
  }
#undef A_ADDR

  // epilogue: relu -> hc (row-major, chunk-local rows)
#pragma unroll
  for (int mr = 0; mr < 4; ++mr)
#pragma unroll
    for (int cb = 0; cb < 8; ++cb) {
      const int col = w * 128 + cb * 16 + l16;
#pragma unroll
      for (int rr = 0; rr < 4; ++rr) {
        const int row = lrowBase + mr * 16 + quad * 4 + rr;
        const float v = fmaxf(acc[mr][cb][rr] + bv[cb], 0.0f);
        hc[(size_t)row * 1024 + col] = f2b(v);
      }
    }
}

// ---------------------------------------------------------------------------
// FUSED MID KERNEL: enc2 + A3-build + dec1 + dec2 in one dispatch.
// Block = 64-row slab (grid = R/64 = 256 -> 1 block/CU on all CUs).
// Phases E (enc2) and D (dec1) are the proven round-3 code, unchanged.
// Phase F (dec2, NEW): C(64x768) = sigmoid(hd @ DW2t^T + b4) -> recon.
//   No LDS, no barriers: waves own 96 private cols; A = own-block hd rows
//   (written by D, L2-hot) and B = DW2t both load DIRECTLY to registers
//   (16B/lane, 16 rows x 64B segments). D->F fence: vmcnt(0)+__syncthreads.
// ---------------------------------------------------------------------------
__global__ __launch_bounds__(512, 2) void gemm_mid(u16* hio,
    const u16* __restrict__ EW2t, const u16* __restrict__ W3t,
    const u16* __restrict__ DW2t, const void* __restrict__ c,
    const void* __restrict__ eb2, const void* __restrict__ db1,
    const void* __restrict__ db2, float* __restrict__ out2,
    float* __restrict__ outR, int rowOff, const int* __restrict__ flag) {
  extern __shared__ __align__(16) u16 lds[];
  const int bid = blockIdx.x;
  const int lrowBase = bid * 64;                 // chunk-local rows
  const int growBase = rowOff + lrowBase;        // global rows
  const int tid = threadIdx.x;
  const int lane = tid & 63, w = tid >> 6;
  const int l16 = lane & 15, quad = lane >> 4;
  const int swq = quad ^ ((l16 >> 1) & 3);
  const int wm = w >> 2, wn4 = w & 3;            // phase-D partition (2M x 4N)

  // ---- preload all scalar operands, then drain (exact ledgers after) ----
  const int isf = *flag;
  float bv2[2], bv3[8][2];
#pragma unroll
  for (int nr = 0; nr < 2; ++nr)
    bv2[nr] = ld_in(eb2, w * 32 + nr * 16 + l16, isf);
#pragma unroll
  for (int np = 0; np < 8; ++np)
#pragma unroll
    for (int nr = 0; nr < 2; ++nr)
      bv3[np][nr] = ld_in(db1, np * 128 + wn4 * 32 + nr * 16 + l16, isf);
  asm volatile("s_waitcnt vmcnt(0)" ::: "memory");

  // ---- phase-E staging maps (BK=64: 8 chunks/row, swizzle low 2 bits) ----
  const int rA = tid >> 3, rcA = tid & 7;
  const int gcA = (rcA & 4) | ((rcA & 3) ^ ((rA >> 1) & 3));
  const u16* gAe = hio + (size_t)(lrowBase + rA) * 1024 + gcA * 8;
  const u16* gBe[4];
#pragma unroll
  for (int j = 0; j < 4; ++j) {
    const int sb = tid + j * 512;
    const int rB = sb >> 3, rcB = sb & 7;
    const int gcB = (rcB & 4) | ((rcB & 3) ^ ((rB >> 1) & 3));
    gBe[j] = EW2t + (size_t)rB * 1024 + gcB * 8;
  }

#define STGE(tt, s) do {                                                   \
    async_cp16(gAe + (tt) * 64, lds + (s) * 4096 + tid * 8);               \
    _Pragma("unroll") for (int j = 0; j < 4; ++j)                          \
      async_cp16(gBe[j] + (tt) * 64,                                       \
                 lds + 8192 + (s) * 16384 + (tid + j * 512) * 8);          \
  } while (0)

  // ---- phase E: 16 K-steps, dbuf ----
  f32x4 acce[4][2] = {};
  STGE(0, 0);
  int p = 0;
  for (int t = 0; t < 16; ++t) {
    if (t + 1 < 16) {
      STGE(t + 1, p ^ 1);
      asm volatile("s_waitcnt vmcnt(5)\n\ts_barrier" ::: "memory");
    } else {
      asm volatile("s_waitcnt vmcnt(0)\n\ts_barrier" ::: "memory");
    }
    const u16* AE = lds + p * 4096;
    const u16* BE = lds + 8192 + p * 16384;
    bf16x8 ae[4][2], be[2][2];
#pragma unroll
    for (int mr = 0; mr < 4; ++mr)
#pragma unroll
      for (int ks = 0; ks < 2; ++ks)
        ae[mr][ks] = *(const bf16x8*)(AE + (mr * 16 + l16) * 64 + ((ks * 4) | swq) * 8);
#pragma unroll
    for (int nr = 0; nr < 2; ++nr)
#pragma unroll
      for (int ks = 0; ks < 2; ++ks)
        be[nr][ks] = *(const bf16x8*)(BE + (w * 32 + nr * 16 + l16) * 64 + ((ks * 4) | swq) * 8);
    asm volatile("s_waitcnt lgkmcnt(0)" ::: "memory");
    __builtin_amdgcn_sched_barrier(0);
    __builtin_amdgcn_s_setprio(1);
#pragma unroll
    for (int mr = 0; mr < 4; ++mr)
#pragma unroll
      for (int nr = 0; nr < 2; ++nr)
#pragma unroll
        for (int ks = 0; ks < 2; ++ks)
          acce[mr][nr] = __builtin_amdgcn_mfma_f32_16x16x32_bf16(ae[mr][ks], be[nr][ks], acce[mr][nr], 0, 0, 0);
    __builtin_amdgcn_s_setprio(0);
    __builtin_amdgcn_sched_barrier(0);
    __builtin_amdgcn_s_barrier();
    p ^= 1;
  }
#undef STGE

  // ---- epilogue E: mu_logvar f32 scatter + mu -> A3 LDS ----
  u16* A3 = lds + 40960;
#pragma unroll
  for (int mr = 0; mr < 4; ++mr)
#pragma unroll
    for (int nr = 0; nr < 2; ++nr) {
      const int col = w * 32 + nr * 16 + l16;
      const int row0 = mr * 16 + quad * 4;
#pragma unroll
      for (int r = 0; r < 4; ++r) {
        const int row = row0 + r;
        const int grow = growBase + row;
        const float v = acce[mr][nr][r] + bv2[nr];
        out2[(size_t)(grow >> 4) * 4096 + col * 16 + (grow & 15)] = v;
        if (col < 128) A3[row * 168 + col] = f2b(v);
      }
    }
  // c-columns 128..137, zeros to 167
  {
    const int rT = tid >> 3, cg = tid & 7;
    const int b = (growBase + rT) >> 4;
#pragma unroll
    for (int jj = 0; jj < 5; ++jj) {
      const int col = 128 + cg * 5 + jj;
      A3[rT * 168 + col] = (col < 138) ? f2b(ld_in(c, (size_t)b * 10 + col - 128, isf)) : (u16)0;
    }
  }
  asm volatile("s_waitcnt vmcnt(0) lgkmcnt(0)" ::: "memory");
  __builtin_amdgcn_s_barrier();

  // ---- phase D: dec1 over 8 col-panels of 128, W3 dbuf in LDS ----
  int nW[5], cW[5];
#pragma unroll
  for (int j = 0; j < 5; ++j) {
    const int s5 = tid + j * 512;
    nW[j] = s5 / 20;                 // 160 u16/row = 20 chunks of 8
    cW[j] = s5 - nW[j] * 20;
  }
#pragma unroll
  for (int j = 0; j < 5; ++j)
    async_cp16(W3t + (size_t)nW[j] * 160 + cW[j] * 8, lds + (tid + j * 512) * 8);
  asm volatile("s_waitcnt vmcnt(0)" ::: "memory");
  __builtin_amdgcn_s_barrier();

  for (int np = 0; np < 8; ++np) {
    const int pb = np & 1;
    if (np < 7) {
#pragma unroll
      for (int j = 0; j < 5; ++j)
        async_cp16(W3t + (size_t)((np + 1) * 128 + nW[j]) * 160 + cW[j] * 8,
                   lds + (pb ^ 1) * 20480 + (tid + j * 512) * 8);
    }
    f32x4 accd[2][2] = {};
    const u16* WP = lds + pb * 20480;
#pragma unroll
    for (int t = 0; t < 5; ++t) {
      bf16x8 ad[2], bd[2];
#pragma unroll
      for (int mr = 0; mr < 2; ++mr)
        ad[mr] = *(const bf16x8*)(A3 + (wm * 32 + mr * 16 + l16) * 168 + (t * 4 + quad) * 8);
#pragma unroll
      for (int nr = 0; nr < 2; ++nr)
        bd[nr] = *(const bf16x8*)(WP + (wn4 * 32 + nr * 16 + l16) * 160 + (t * 4 + quad) * 8);
      asm volatile("s_waitcnt lgkmcnt(0)" ::: "memory");
      __builtin_amdgcn_sched_barrier(0);
#pragma unroll
      for (int mr = 0; mr < 2; ++mr)
#pragma unroll
        for (int nr = 0; nr < 2; ++nr)
          accd[mr][nr] = __builtin_amdgcn_mfma_f32_16x16x32_bf16(ad[mr], bd[nr], accd[mr][nr], 0, 0, 0);
    }
    // epilogue: relu -> hd in place (16 stores/thread)
#pragma unroll
    for (int mr = 0; mr < 2; ++mr)
#pragma unroll
      for (int nr = 0; nr < 2; ++nr) {
        const int col = np * 128 + wn4 * 32 + nr * 16 + l16;
        const int row0 = wm * 32 + mr * 16 + quad * 4;
#pragma unroll
        for (int r = 0; r < 4; ++r) {
          const int row = row0 + r;
          const float v = fmaxf(accd[mr][nr][r] + bv3[np][nr], 0.0f);
          hio[(size_t)(lrowBase + row) * 1024 + col] = f2b(v);
        }
      }
    if (np < 7) {
      // 5 stage loads issued BEFORE the 16 stores: vmcnt(16) => stages done
      asm volatile("s_waitcnt vmcnt(16)" ::: "memory");
      __builtin_amdgcn_s_barrier();
    }
  }

  // ---- phase F: dec2 (NEW). hd rows are ours, L2-hot; B = DW2t from L2.
  // Fence: all hd stores retired + block-wide visibility.
  asm volatile("s_waitcnt vmcnt(0) lgkmcnt(0)" ::: "memory");
  __syncthreads();

  float bvF[6];
#pragma unroll
  for (int cb = 0; cb < 6; ++cb)
    bvF[cb] = ld_in(db2, w * 96 + cb * 16 + l16, isf);

  f32x4 accf[4][6] = {};
  const u16* hA = hio + (size_t)lrowBase * 1024;
  const u16* aB[4];
#pragma unroll
  for (int mr = 0; mr < 4; ++mr)
    aB[mr] = hA + (mr * 16 + l16) * 1024 + quad * 8;
  const u16* bBF[6];
#pragma unroll
  for (int cb = 0; cb < 6; ++cb)
    bBF[cb] = DW2t + (size_t)(w * 96 + cb * 16 + l16) * 1024 + quad * 8;

#pragma unroll 4
  for (int t = 0; t < 32; ++t) {
    bf16x8 af[4], bff[6];
#pragma unroll
    for (int mr = 0; mr < 4; ++mr) af[mr] = *(const bf16x8*)(aB[mr] + t * 32);
#pragma unroll
    for (int cb = 0; cb < 6; ++cb) bff[cb] = *(const bf16x8*)(bBF[cb] + t * 32);
#pragma unroll
    for (int mr = 0; mr < 4; ++mr)
#pragma unroll
      for (int cb = 0; cb < 6; ++cb)
        accf[mr][cb] = __builtin_amdgcn_mfma_f32_16x16x32_bf16(af[mr], bff[cb], accf[mr][cb], 0, 0, 0);
  }

  // epilogue F: sigmoid -> recon scatter
#pragma unroll
  for (int mr = 0; mr < 4; ++mr)
#pragma unroll
    for (int cb = 0; cb < 6; ++cb) {
      const int col = w * 96 + cb * 16 + l16;
      const int ch = col >> 8, kh = (col >> 4) & 15, kw = col & 15;
#pragma unroll
      for (int r = 0; r < 4; ++r) {
        const int grow = growBase + mr * 16 + quad * 4 + r;
        float v = accf[mr][cb][r] + bvF[cb];
        v = 1.0f / (1.0f + __expf(-v));
        const int bb = grow >> 4, l = grow & 15;
        const int oh = l >> 2, ow = l & 3;
        outR[(size_t)bb * 12288 + ch * 4096 + (oh * 16 + kh) * 64 + ow * 16 + kw] = v;
      }
    }
}

// ---------------------------------------------------------------------------
// Workspace (u16 element offsets):
//   flag @ 0 (8 u16) | W1t 1024x800 | EW2t 256x1024 | W3t 1024x160
//   DW2t 768x1024 | xb 1024x12544 | hc Rx1024 (h, overwritten in-place by hd)
// bytes = 2*(2031624 + 12845056 + R*1024); R=16384 -> 63.3 MB (ws = 256 MB)
// ---------------------------------------------------------------------------

extern "C" void kernel_launch(void* const* d_in, const int* in_sizes, int n_in,
                              void* d_out, int out_size, void* d_ws, size_t ws_size,
                              hipStream_t stream) {
  const void* x   = d_in[0];
  const void* c   = d_in[1];
  const void* ew1 = d_in[2];
  const void* eb1 = d_in[3];
  const void* ew2 = d_in[4];
  const void* eb2 = d_in[5];
  const void* dw1 = d_in[6];
  const void* db1 = d_in[7];
  const void* dw2 = d_in[8];
  const void* db2 = d_in[9];
  float* out  = (float*)d_out;
  u16*   ws   = (u16*)d_ws;

  static bool configured = false;
  if (!configured) {
    hipFuncSetAttribute(reinterpret_cast<const void*>(gemm_mid),
                        hipFuncAttributeMaxDynamicSharedMemorySize, 103424);
    configured = true;
  }

  const size_t fixedU16 = 8 + 819200 + 262144 + 163840 + 786432 + 12845056;
  int R = 2048;
  for (int cand = 16384; cand >= 2048; cand >>= 1) {
    if ((fixedU16 + (size_t)cand * 1024) * 2 <= ws_size) { R = cand; break; }
  }

  int* flag = (int*)ws;
  u16* W1t  = ws + 8;
  u16* EW2t = W1t + 819200;
  u16* W3t  = EW2t + 262144;
  u16* DW2t = W3t + 163840;
  u16* xb   = DW2t + 786432;
  u16* hc   = xb + 12845056;
  float* out2 = out + RECON_ELEMS;

  detect_f32<<<dim3(1), dim3(256), 0, stream>>>((const u16*)x, flag);

  cvt_x<<<dim3(6272), dim3(256), 0, stream>>>(x, c, xb, flag);

  prep_weights<<<dim3(32, 32, 4), dim3(256), 0, stream>>>(ew1, ew2, dw1, dw2,
                                                          W1t, EW2t, W3t, DW2t, flag);

  const int chunks = 16384 / R;
  for (int chunk = 0; chunk < chunks; ++chunk) {
    int rowOff = chunk * R;
    // enc1: h = relu(patch(x)|c @ W1 + b1), direct-B streaming kernel
    enc1_k<<<dim3(R / 64), dim3(512), 0, stream>>>(xb, W1t, eb1, hc, rowOff, flag);
    // enc2 + A3 + dec1 + dec2 fused (mu_logvar scatter, hd in-place, recon)
    gemm_mid<<<dim3(R / 64), dim3(512), 103424, stream>>>(hc, EW2t, W3t, DW2t, c,
                                                          eb2, db1, db2, out2, out,
                                                          rowOff, flag);
  }
}

// Round 6
// 244.782 us; speedup vs baseline: 1.2799x; 1.2799x over previous
//
#include <hip/hip_runtime.h>

typedef unsigned short u16;
typedef unsigned int   u32;
typedef __bf16 bf16x8 __attribute__((ext_vector_type(8)));
typedef float  f32x4  __attribute__((ext_vector_type(4)));

__device__ __forceinline__ u16 f2b(float f) {
  u32 u = __builtin_bit_cast(u32, f);
  u = (u + 0x7fffu + ((u >> 16) & 1u)) >> 16;   // RNE
  return (u16)u;
}
__device__ __forceinline__ float b2f(u16 h) {
  u32 u = ((u32)h) << 16;
  return __builtin_bit_cast(float, u);
}
__device__ __forceinline__ float ld_in(const void* p, size_t idx, int isf32) {
  return isf32 ? ((const float*)p)[idx] : b2f(((const u16*)p)[idx]);
}
// async 16B global->LDS; HW semantics: LDS dest = wave-uniform base + lane*16
__device__ __forceinline__ void async_cp16(const u16* g, u16* l) {
  __builtin_amdgcn_global_load_lds(
      (const __attribute__((address_space(1))) void*)g,
      (__attribute__((address_space(3))) void*)l, 16, 0, 0);
}

// Constants: BS=1024, CH=3, IMG=64, K=16, NC=10, HID=1024, LAT=128
// OH=4, L=16, PD=768, M=16384.
#define RECON_ELEMS 12582912   // 1024*3*64*64
// xb: per batch 12544 bf16 = [image 12288 | c 10 | zeros 246]
#define XB_STRIDE 12544

// ---------------------------------------------------------------------------
// dtype detector: bf16 uniform[0,1) values are u16 in [0,0x3F80], sign=0.
// ---------------------------------------------------------------------------
__global__ __launch_bounds__(256) void detect_f32(const u16* __restrict__ x,
                                                  int* __restrict__ flag) {
  __shared__ int s;
  if (threadIdx.x == 0) s = 0;
  __syncthreads();
  int bad = 0;
  for (int i = threadIdx.x; i < 2048; i += 256) {
    u16 u = x[i];
    if ((u & 0x8000u) || (u > 0x3F80u)) bad = 1;
  }
  if (bad) atomicOr(&s, 1);
  __syncthreads();
  if (threadIdx.x == 0) *flag = s;
}

// ---------------------------------------------------------------------------
// cvt_x: x (f32 or bf16) -> xb bf16 [12288 image | c(10) | zeros(246)] / batch.
// enc1 stages A-tiles straight from xb (per-lane gload_lds source addresses
// carry the patch permutation). 75MB traffic, memory-bound.
// ---------------------------------------------------------------------------
__global__ __launch_bounds__(256) void cvt_x(const void* __restrict__ x,
                                             const void* __restrict__ c,
                                             u16* __restrict__ xb,
                                             const int* __restrict__ flag) {
  const int g = blockIdx.x * 256 + threadIdx.x;
  const int isf = *flag;
  if (g < 1572864) {                       // 12582912/8 image groups of 8
    const size_t i = (size_t)g * 8;
    const int b = (int)(i / 12288);
    const int r = (int)(i - (size_t)b * 12288);
    u16* dst = xb + (size_t)b * XB_STRIDE + r;
    if (isf) {
      const float* s = (const float*)x + i;
      float4 f0 = *(const float4*)(s);
      float4 f1 = *(const float4*)(s + 4);
      dst[0] = f2b(f0.x); dst[1] = f2b(f0.y); dst[2] = f2b(f0.z); dst[3] = f2b(f0.w);
      dst[4] = f2b(f1.x); dst[5] = f2b(f1.y); dst[6] = f2b(f1.z); dst[7] = f2b(f1.w);
    } else {
      *(int4*)dst = *(const int4*)((const u16*)x + i);
    }
  } else if (g < 1605632) {                // tail: 1024 batches x 32 groups
    const int t8 = g - 1572864;
    const int b = t8 >> 5;
    const int k8 = (t8 & 31) * 8;
    u16* dst = xb + (size_t)b * XB_STRIDE + 12288 + k8;
#pragma unroll
    for (int j = 0; j < 8; ++j) {
      const int col = k8 + j;
      dst[j] = (col < 10) ? f2b(ld_in(c, (size_t)b * 10 + col, isf)) : (u16)0;
    }
  }
}

// ---------------------------------------------------------------------------
// Fused weight prep: 4 transposes in one dispatch (blockIdx.z selects).
// dst (N x Kpad) = src(Ksrc x N)^T, zero-pad k>=Ksrc. 32x32 LDS tile.
// ---------------------------------------------------------------------------
__global__ __launch_bounds__(256) void prep_weights(const void* __restrict__ ew1,
                                                    const void* __restrict__ ew2,
                                                    const void* __restrict__ dw1,
                                                    const void* __restrict__ dw2,
                                                    u16* __restrict__ W1t,
                                                    u16* __restrict__ EW2t,
                                                    u16* __restrict__ W3t,
                                                    u16* __restrict__ DW2t,
                                                    const int* __restrict__ flag) {
  const int z = blockIdx.z;
  const void* src; u16* dst; int N, Kpad, Ksrc;
  if (z == 0)      { src = ew1; dst = W1t;  N = 1024; Kpad = 800;  Ksrc = 778;  }
  else if (z == 1) { src = ew2; dst = EW2t; N = 256;  Kpad = 1024; Ksrc = 1024; }
  else if (z == 2) { src = dw1; dst = W3t;  N = 1024; Kpad = 160;  Ksrc = 138;  }
  else             { src = dw2; dst = DW2t; N = 768;  Kpad = 1024; Ksrc = 1024; }
  const int k0 = blockIdx.x * 32, n0 = blockIdx.y * 32;
  if (k0 >= Kpad || n0 >= N) return;
  __shared__ float t[32][33];
  const int tx = threadIdx.x & 31, ty = threadIdx.x >> 5;   // 32 x 8
  const int isf = *flag;
#pragma unroll
  for (int j = 0; j < 4; ++j) {
    int k = k0 + ty + j * 8;
    t[ty + j * 8][tx] = (k < Ksrc) ? ld_in(src, (size_t)k * N + n0 + tx, isf) : 0.0f;
  }
  __syncthreads();
#pragma unroll
  for (int j = 0; j < 4; ++j) {
    int n = n0 + ty + j * 8;
    dst[(size_t)n * Kpad + k0 + tx] = f2b(t[tx][ty + j * 8]);
  }
}

// ---------------------------------------------------------------------------
// Ring-3 128xBN / BK=32 GEMM: EXACT round-2..4 proven schedule (one barrier +
// MFMA cluster per K-step, 3-buffer LDS, 2-full-step prefetch lead, proven
// swizzle pair), but tile shrunk to 128xBN with 4 waves (256 thr) so LDS =
// 3*(8KB + BN*64B) = 72/60 KB -> 2 BLOCKS/CU. Mechanism under test: fill the
// barrier-drain dead time with the co-resident block + fill all 256 CUs
// (dec2 was 192 blocks). Per-wave per-step work unchanged vs round-4 r3.
// Waves 2Mx2N, per-wave 64 x BN/2, frags a[4] x b[BN/32].
// Loads/thread/step LPT = 2 + BN/64 (A 2, B BN/64). vmcnt(LPT) at step end.
// AMODE: 0 = plain row-major A (ld=K); 1 = xb patch-gather (proven round-4).
// EPI: 0 = ReLU -> bf16 outb (ld = NBX*BN); 2 = sigmoid -> f32 recon scatter.
// ---------------------------------------------------------------------------
template <int EPI, int AMODE, int BN>
__global__ __launch_bounds__(256, 2) void gemm_r3b(const u16* __restrict__ A,
                                                   const u16* __restrict__ Bt,
                                                   const void* __restrict__ bias,
                                                   u16* __restrict__ outb,
                                                   float* __restrict__ outf,
                                                   int K, int NBX, int NBY,
                                                   int rowOff,
                                                   const int* __restrict__ flag) {
  constexpr int TS  = 4096 + BN * 32;   // u16 per tile buffer (A + B)
  constexpr int CB  = BN / 32;          // per-wave col frags
  constexpr int NBC = BN / 64;          // B staging calls per thread
  constexpr int LPT = 2 + NBC;          // loads per thread per tile
  extern __shared__ __align__(16) u16 lds[];   // 3 * TS

  const int bid = blockIdx.x;
  const int xcd = bid & 7, idx = bid >> 3;
  const int byl = idx / NBX;
  const int by = xcd * (NBY >> 3) + byl;
  const int bx = idx - byl * NBX;
  const int rowBase = by * 128, colBase = bx * BN;
  const int N = NBX * BN;

  const int tid = threadIdx.x;
  const int lane = tid & 63, w = tid >> 6;
  const int l16 = lane & 15, quad = lane >> 4;
  const int wm = w >> 1, wn = w & 1;            // 2 x 2 waves
  const int swq = quad ^ ((l16 >> 1) & 3);      // XOR-swizzled chunk slot

  const int isf = *flag;
  float bv[CB];
#pragma unroll
  for (int cb = 0; cb < CB; ++cb)
    bv[cb] = ld_in(bias, colBase + wn * (BN / 2) + cb * 16 + l16, isf);
  asm volatile("s_waitcnt vmcnt(0)" ::: "memory");

  // staging maps (proven pattern): slot s -> row r=s>>2, chunk q=(s&3)^((r>>1)&3)
  // A: slots tid, tid+256 (512 = 128 rows x 4)
  const int sA0 = tid, sA1 = tid + 256;
  const int rA0 = sA0 >> 2, qA0 = (sA0 & 3) ^ ((rA0 >> 1) & 3);
  const int rA1 = sA1 >> 2, qA1 = (sA1 & 3) ^ ((rA1 >> 1) & 3);
  // B: slots tid + j*256, j < NBC (BN rows x 4)
  const u16* gB[NBC];
#pragma unroll
  for (int j = 0; j < NBC; ++j) {
    const int s = tid + j * 256;
    const int rB = s >> 2, qB = (s & 3) ^ ((rB >> 1) & 3);
    gB[j] = Bt + (size_t)(colBase + rB) * K + qB * 8;
  }
  // A side
  const u16* gA0 = nullptr; const u16* gA1 = nullptr;
  int b1A0 = 0, b2A0 = 0, kq0 = 0, b1A1 = 0, b2A1 = 0, kq1 = 0;
  if (AMODE == 0) {
    gA0 = A + (size_t)(rowBase + rA0) * K + qA0 * 8;
    gA1 = A + (size_t)(rowBase + rA1) * K + qA1 * 8;
  } else {
    const int g0 = rowOff + rowBase + rA0, g1 = rowOff + rowBase + rA1;
    const int bb0 = g0 >> 4, ll0 = g0 & 15;
    const int bb1 = g1 >> 4, ll1 = g1 & 15;
    b1A0 = bb0 * XB_STRIDE + (ll0 >> 2) * 1024 + (ll0 & 3) * 16;
    b1A1 = bb1 * XB_STRIDE + (ll1 >> 2) * 1024 + (ll1 & 3) * 16;
    b2A0 = bb0 * XB_STRIDE + 11520;   // +k -> b*12544+12288+(k-768)
    b2A1 = bb1 * XB_STRIDE + 11520;
    kq0 = qA0 * 8; kq1 = qA1 * 8;
  }
  auto aAddr = [&](int base1, int base2, int kq, int tt) -> const u16* {
    const int k = kq + (tt << 5);
    const int off = (k < 768)
        ? base1 + ((k >> 8) << 12) + (((k >> 4) & 15) << 6) + (k & 15)
        : base2 + k;
    return A + off;
  };
#define STAGE_T(tt, D) do {                                                \
    if (AMODE == 0) {                                                      \
      const int ko_ = (tt) * 32;                                           \
      async_cp16(gA0 + ko_, (D) + tid * 8);                                \
      async_cp16(gA1 + ko_, (D) + 2048 + tid * 8);                         \
    } else {                                                               \
      async_cp16(aAddr(b1A0, b2A0, kq0, (tt)), (D) + tid * 8);             \
      async_cp16(aAddr(b1A1, b2A1, kq1, (tt)), (D) + 2048 + tid * 8);      \
    }                                                                      \
    {                                                                      \
      const int ko_ = (tt) * 32;                                           \
      _Pragma("unroll") for (int j = 0; j < NBC; ++j)                      \
        async_cp16(gB[j] + ko_, (D) + 4096 + j * 2048 + tid * 8);          \
    }                                                                      \
  } while (0)

  f32x4 acc[4][CB] = {};
  bf16x8 a[4], b[CB];
  const int NT = K >> 5;                        // K % 32 == 0

  STAGE_T(0, lds);
  if (NT > 1) {
    STAGE_T(1, lds + TS);
    if constexpr (LPT == 6) asm volatile("s_waitcnt vmcnt(6)" ::: "memory");
    else                    asm volatile("s_waitcnt vmcnt(5)" ::: "memory");
  } else {
    asm volatile("s_waitcnt vmcnt(0)" ::: "memory");
  }
  __builtin_amdgcn_s_barrier();

  int cur = 0;
  for (int t = 0; t < NT; ++t) {
    const u16* Lq = lds + cur * TS;
#pragma unroll
    for (int mr = 0; mr < 4; ++mr)
      a[mr] = *(const bf16x8*)(Lq + (wm * 64 + mr * 16 + l16) * 32 + swq * 8);
#pragma unroll
    for (int cb = 0; cb < CB; ++cb)
      b[cb] = *(const bf16x8*)(Lq + 4096 + (wn * (BN / 2) + cb * 16 + l16) * 32 + swq * 8);
    if (t + 2 < NT) {
      const int d2 = (cur >= 1) ? cur - 1 : 2;    // (cur+2)%3
      STAGE_T(t + 2, lds + d2 * TS);
    }
    asm volatile("s_waitcnt lgkmcnt(0)" ::: "memory");
    __builtin_amdgcn_sched_barrier(0);
    __builtin_amdgcn_s_setprio(1);
#pragma unroll
    for (int mr = 0; mr < 4; ++mr)
#pragma unroll
      for (int cb = 0; cb < CB; ++cb)
        acc[mr][cb] = __builtin_amdgcn_mfma_f32_16x16x32_bf16(a[mr], b[cb], acc[mr][cb], 0, 0, 0);
    __builtin_amdgcn_s_setprio(0);
    __builtin_amdgcn_sched_barrier(0);
    if (t + 2 < NT) {
      if constexpr (LPT == 6) asm volatile("s_waitcnt vmcnt(6)" ::: "memory");
      else                    asm volatile("s_waitcnt vmcnt(5)" ::: "memory");
    } else if (t + 1 < NT) {
      asm volatile("s_waitcnt vmcnt(0)" ::: "memory");
    }
    if (t + 1 < NT) __builtin_amdgcn_s_barrier();
    cur = (cur >= 2) ? 0 : cur + 1;
  }
#undef STAGE_T

#pragma unroll
  for (int mr = 0; mr < 4; ++mr) {
    const int row0 = rowBase + wm * 64 + mr * 16 + quad * 4;
#pragma unroll
    for (int cb = 0; cb < CB; ++cb) {
      const int col = colBase + wn * (BN / 2) + cb * 16 + l16;
#pragma unroll
      for (int r = 0; r < 4; ++r) {
        const int row = row0 + r;                // chunk-local
        float v = acc[mr][cb][r] + bv[cb];
        if (EPI == 0) {
          v = fmaxf(v, 0.0f);
          outb[(size_t)row * N + col] = f2b(v);
        } else {
          v = 1.0f / (1.0f + __expf(-v));
          const int grow = row + rowOff;
          const int bb = grow >> 4, l = grow & 15;
          const int oh = l >> 2, ow = l & 3;
          const int ch = col >> 8, kh = (col >> 4) & 15, kw = col & 15;
          outf[(size_t)bb * 12288 + ch * 4096 + (oh * 16 + kh) * 64 + ow * 16 + kw] = v;
        }
      }
    }
  }
}

// ---------------------------------------------------------------------------
// FUSED MID KERNEL: enc2 + A3-build + dec1 in one dispatch (proven round 3/4,
// exact revert of the round-5 F-phase addition).
// Block = 64-row slab (grid = R/64 = 256 -> 1 block/CU on all CUs).
// ---------------------------------------------------------------------------
__global__ __launch_bounds__(512, 2) void gemm_mid(u16* hio,
    const u16* __restrict__ EW2t, const u16* __restrict__ W3t,
    const void* __restrict__ c, const void* __restrict__ eb2,
    const void* __restrict__ db1, float* __restrict__ out2,
    int rowOff, const int* __restrict__ flag) {
  extern __shared__ __align__(16) u16 lds[];
  const int bid = blockIdx.x;
  const int lrowBase = bid * 64;                 // chunk-local rows
  const int growBase = rowOff + lrowBase;        // global rows
  const int tid = threadIdx.x;
  const int lane = tid & 63, w = tid >> 6;
  const int l16 = lane & 15, quad = lane >> 4;
  const int swq = quad ^ ((l16 >> 1) & 3);
  const int wm = w >> 2, wn4 = w & 3;            // phase-D partition (2M x 4N)

  // ---- preload all scalar operands, then drain (exact ledgers after) ----
  const int isf = *flag;
  float bv2[2], bv3[8][2];
#pragma unroll
  for (int nr = 0; nr < 2; ++nr)
    bv2[nr] = ld_in(eb2, w * 32 + nr * 16 + l16, isf);
#pragma unroll
  for (int np = 0; np < 8; ++np)
#pragma unroll
    for (int nr = 0; nr < 2; ++nr)
      bv3[np][nr] = ld_in(db1, np * 128 + wn4 * 32 + nr * 16 + l16, isf);
  asm volatile("s_waitcnt vmcnt(0)" ::: "memory");

  // ---- phase-E staging maps (BK=64: 8 chunks/row, swizzle low 2 bits) ----
  const int rA = tid >> 3, rcA = tid & 7;
  const int gcA = (rcA & 4) | ((rcA & 3) ^ ((rA >> 1) & 3));
  const u16* gAe = hio + (size_t)(lrowBase + rA) * 1024 + gcA * 8;
  const u16* gBe[4];
#pragma unroll
  for (int j = 0; j < 4; ++j) {
    const int sb = tid + j * 512;
    const int rB = sb >> 3, rcB = sb & 7;
    const int gcB = (rcB & 4) | ((rcB & 3) ^ ((rB >> 1) & 3));
    gBe[j] = EW2t + (size_t)rB * 1024 + gcB * 8;
  }

#define STGE(tt, s) do {                                                   \
    async_cp16(gAe + (tt) * 64, lds + (s) * 4096 + tid * 8);               \
    _Pragma("unroll") for (int j = 0; j < 4; ++j)                          \
      async_cp16(gBe[j] + (tt) * 64,                                       \
                 lds + 8192 + (s) * 16384 + (tid + j * 512) * 8);          \
  } while (0)

  // ---- phase E: 16 K-steps, dbuf ----
  f32x4 acce[4][2] = {};
  STGE(0, 0);
  int p = 0;
  for (int t = 0; t < 16; ++t) {
    if (t + 1 < 16) {
      STGE(t + 1, p ^ 1);
      asm volatile("s_waitcnt vmcnt(5)\n\ts_barrier" ::: "memory");
    } else {
      asm volatile("s_waitcnt vmcnt(0)\n\ts_barrier" ::: "memory");
    }
    const u16* AE = lds + p * 4096;
    const u16* BE = lds + 8192 + p * 16384;
    bf16x8 ae[4][2], be[2][2];
#pragma unroll
    for (int mr = 0; mr < 4; ++mr)
#pragma unroll
      for (int ks = 0; ks < 2; ++ks)
        ae[mr][ks] = *(const bf16x8*)(AE + (mr * 16 + l16) * 64 + ((ks * 4) | swq) * 8);
#pragma unroll
    for (int nr = 0; nr < 2; ++nr)
#pragma unroll
      for (int ks = 0; ks < 2; ++ks)
        be[nr][ks] = *(const bf16x8*)(BE + (w * 32 + nr * 16 + l16) * 64 + ((ks * 4) | swq) * 8);
    asm volatile("s_waitcnt lgkmcnt(0)" ::: "memory");
    __builtin_amdgcn_sched_barrier(0);
    __builtin_amdgcn_s_setprio(1);
#pragma unroll
    for (int mr = 0; mr < 4; ++mr)
#pragma unroll
      for (int nr = 0; nr < 2; ++nr)
#pragma unroll
        for (int ks = 0; ks < 2; ++ks)
          acce[mr][nr] = __builtin_amdgcn_mfma_f32_16x16x32_bf16(ae[mr][ks], be[nr][ks], acce[mr][nr], 0, 0, 0);
    __builtin_amdgcn_s_setprio(0);
    __builtin_amdgcn_sched_barrier(0);
    __builtin_amdgcn_s_barrier();
    p ^= 1;
  }
#undef STGE

  // ---- epilogue E: mu_logvar f32 scatter + mu -> A3 LDS ----
  u16* A3 = lds + 40960;
#pragma unroll
  for (int mr = 0; mr < 4; ++mr)
#pragma unroll
    for (int nr = 0; nr < 2; ++nr) {
      const int col = w * 32 + nr * 16 + l16;
      const int row0 = mr * 16 + quad * 4;
#pragma unroll
      for (int r = 0; r < 4; ++r) {
        const int row = row0 + r;
        const int grow = growBase + row;
        const float v = acce[mr][nr][r] + bv2[nr];
        out2[(size_t)(grow >> 4) * 4096 + col * 16 + (grow & 15)] = v;
        if (col < 128) A3[row * 168 + col] = f2b(v);
      }
    }
  // c-columns 128..137, zeros to 167
  {
    const int rT = tid >> 3, cg = tid & 7;
    const int b = (growBase + rT) >> 4;
#pragma unroll
    for (int jj = 0; jj < 5; ++jj) {
      const int col = 128 + cg * 5 + jj;
      A3[rT * 168 + col] = (col < 138) ? f2b(ld_in(c, (size_t)b * 10 + col - 128, isf)) : (u16)0;
    }
  }
  asm volatile("s_waitcnt vmcnt(0) lgkmcnt(0)" ::: "memory");
  __builtin_amdgcn_s_barrier();

  // ---- phase D: dec1 over 8 col-panels of 128, W3 dbuf in LDS ----
  int nW[5], cW[5];
#pragma unroll
  for (int j = 0; j < 5; ++j) {
    const int s5 = tid + j * 512;
    nW[j] = s5 / 20;                 // 160 u16/row = 20 chunks of 8
    cW[j] = s5 - nW[j] * 20;
  }
#pragma unroll
  for (int j = 0; j < 5; ++j)
    async_cp16(W3t + (size_t)nW[j] * 160 + cW[j] * 8, lds + (tid + j * 512) * 8);
  asm volatile("s_waitcnt vmcnt(0)" ::: "memory");
  __builtin_amdgcn_s_barrier();

  for (int np = 0; np < 8; ++np) {
    const int pb = np & 1;
    if (np < 7) {
#pragma unroll
      for (int j = 0; j < 5; ++j)
        async_cp16(W3t + (size_t)((np + 1) * 128 + nW[j]) * 160 + cW[j] * 8,
                   lds + (pb ^ 1) * 20480 + (tid + j * 512) * 8);
    }
    f32x4 accd[2][2] = {};
    const u16* WP = lds + pb * 20480;
#pragma unroll
    for (int t = 0; t < 5; ++t) {
      bf16x8 ad[2], bd[2];
#pragma unroll
      for (int mr = 0; mr < 2; ++mr)
        ad[mr] = *(const bf16x8*)(A3 + (wm * 32 + mr * 16 + l16) * 168 + (t * 4 + quad) * 8);
#pragma unroll
      for (int nr = 0; nr < 2; ++nr)
        bd[nr] = *(const bf16x8*)(WP + (wn4 * 32 + nr * 16 + l16) * 160 + (t * 4 + quad) * 8);
      asm volatile("s_waitcnt lgkmcnt(0)" ::: "memory");
      __builtin_amdgcn_sched_barrier(0);
#pragma unroll
      for (int mr = 0; mr < 2; ++mr)
#pragma unroll
        for (int nr = 0; nr < 2; ++nr)
          accd[mr][nr] = __builtin_amdgcn_mfma_f32_16x16x32_bf16(ad[mr], bd[nr], accd[mr][nr], 0, 0, 0);
    }
    // epilogue: relu -> hd in place (16 stores/thread)
#pragma unroll
    for (int mr = 0; mr < 2; ++mr)
#pragma unroll
      for (int nr = 0; nr < 2; ++nr) {
        const int col = np * 128 + wn4 * 32 + nr * 16 + l16;
        const int row0 = wm * 32 + mr * 16 + quad * 4;
#pragma unroll
        for (int r = 0; r < 4; ++r) {
          const int row = row0 + r;
          const float v = fmaxf(accd[mr][nr][r] + bv3[np][nr], 0.0f);
          hio[(size_t)(lrowBase + row) * 1024 + col] = f2b(v);
        }
      }
    if (np < 7) {
      // 5 stage loads issued BEFORE the 16 stores: vmcnt(16) => stages done
      asm volatile("s_waitcnt vmcnt(16)" ::: "memory");
      __builtin_amdgcn_s_barrier();
    }
  }
}

// ---------------------------------------------------------------------------
// Workspace (u16 element offsets):
//   flag @ 0 (8 u16) | W1t 1024x800 | EW2t 256x1024 | W3t 1024x160
//   DW2t 768x1024 | xb 1024x12544 | hc Rx1024 (h, overwritten in-place by hd)
// bytes = 2*(2031624 + 12845056 + R*1024); R=16384 -> 63.3 MB (ws = 256 MB)
// ---------------------------------------------------------------------------

extern "C" void kernel_launch(void* const* d_in, const int* in_sizes, int n_in,
                              void* d_out, int out_size, void* d_ws, size_t ws_size,
                              hipStream_t stream) {
  const void* x   = d_in[0];
  const void* c   = d_in[1];
  const void* ew1 = d_in[2];
  const void* eb1 = d_in[3];
  const void* ew2 = d_in[4];
  const void* eb2 = d_in[5];
  const void* dw1 = d_in[6];
  const void* db1 = d_in[7];
  const void* dw2 = d_in[8];
  const void* db2 = d_in[9];
  float* out  = (float*)d_out;
  u16*   ws   = (u16*)d_ws;

  static bool configured = false;
  if (!configured) {
    hipFuncSetAttribute(reinterpret_cast<const void*>(gemm_r3b<0, 1, 256>),
                        hipFuncAttributeMaxDynamicSharedMemorySize, 73728);
    hipFuncSetAttribute(reinterpret_cast<const void*>(gemm_r3b<2, 0, 192>),
                        hipFuncAttributeMaxDynamicSharedMemorySize, 61440);
    hipFuncSetAttribute(reinterpret_cast<const void*>(gemm_mid),
                        hipFuncAttributeMaxDynamicSharedMemorySize, 103424);
    configured = true;
  }

  const size_t fixedU16 = 8 + 819200 + 262144 + 163840 + 786432 + 12845056;
  int R = 2048;
  for (int cand = 16384; cand >= 2048; cand >>= 1) {
    if ((fixedU16 + (size_t)cand * 1024) * 2 <= ws_size) { R = cand; break; }
  }

  int* flag = (int*)ws;
  u16* W1t  = ws + 8;
  u16* EW2t = W1t + 819200;
  u16* W3t  = EW2t + 262144;
  u16* DW2t = W3t + 163840;
  u16* xb   = DW2t + 786432;
  u16* hc   = xb + 12845056;
  float* out2 = out + RECON_ELEMS;

  detect_f32<<<dim3(1), dim3(256), 0, stream>>>((const u16*)x, flag);

  cvt_x<<<dim3(6272), dim3(256), 0, stream>>>(x, c, xb, flag);

  prep_weights<<<dim3(32, 32, 4), dim3(256), 0, stream>>>(ew1, ew2, dw1, dw2,
                                                          W1t, EW2t, W3t, DW2t, flag);

  const int chunks = 16384 / R;
  for (int chunk = 0; chunk < chunks; ++chunk) {
    int rowOff = chunk * R;
    const int NBY = R / 128;   // 128-row blocks (NBY%8==0)
    // enc1: h = relu(patch(x)|c @ W1 + b1), N=1024 K=800 (128x256, 2 blk/CU)
    gemm_r3b<0, 1, 256><<<dim3(4 * NBY), dim3(256), 73728, stream>>>(
        xb, W1t, eb1, hc, nullptr, 800, 4, NBY, rowOff, flag);
    // enc2 + A3 + dec1 fused: mu_logvar scatter + hd (in-place in hc)
    gemm_mid<<<dim3(R / 64), dim3(512), 103424, stream>>>(hc, EW2t, W3t, c, eb2, db1,
                                                          out2, rowOff, flag);
    // dec2: recon = sigmoid(hd @ W4 + b4), N=768 K=1024 (128x192, 2 blk/CU)
    gemm_r3b<2, 0, 192><<<dim3(4 * NBY), dim3(256), 61440, stream>>>(
        hc, DW2t, db2, nullptr, out, 1024, 4, NBY, rowOff, flag);
  }
}